// Round 3
// baseline (825.477 us; speedup 1.0000x reference)
//
#include <hip/hip_runtime.h>
#include <math.h>
#include <stdint.h>

#define NBATCH 8
#define HGRID 128
#define DCH 256
#define NPTS 8192
#define INDIM 813
#define K0P 832
#define TOTROWS (NBATCH * NPTS)

typedef __attribute__((ext_vector_type(8))) short short8;
typedef __attribute__((ext_vector_type(16))) float f32x16;

// ---------- bf16 helpers ----------
__device__ __forceinline__ unsigned short bf16_rne(float f) {
  unsigned int u = __float_as_uint(f);
  u += 0x7fffu + ((u >> 16) & 1u);
  return (unsigned short)(u >> 16);
}
__device__ __forceinline__ float b2f(unsigned short h) {
  return __uint_as_float(((unsigned int)h) << 16);
}
__device__ __forceinline__ void split_bf16(float v, unsigned short& hi, unsigned short& lo) {
  hi = bf16_rne(v);
  lo = bf16_rne(v - b2f(hi));
}

__device__ __forceinline__ float gelu_f(float x) {
  float u = 0.7978845608028654f * (x + 0.044715f * x * x * x);
  float au = fabsf(u);
  float e = __expf(-2.0f * au);
  float t = 1.0f - 2.0f * e / (1.0f + e);
  t = copysignf(t, u);
  return 0.5f * x * (1.0f + t);
}

// ---------- async global->LDS 16B ----------
__device__ __forceinline__ void gload16(const void* g, void* l) {
  __builtin_amdgcn_global_load_lds(
      (const __attribute__((address_space(1))) unsigned int*)g,
      (__attribute__((address_space(3))) unsigned int*)l, 16, 0, 0);
}

// ---------------- ctx: gamma/beta ----------------
__global__ __launch_bounds__(256) void ctx_kernel(
    const float* __restrict__ cv, const float* __restrict__ cw,
    const float* __restrict__ cb, float* __restrict__ gb) {
  int b = blockIdx.x;
  int t = threadIdx.x;
  for (int half = 0; half < 2; ++half) {
    int j = half * 256 + t;
    float acc = cb[j];
    for (int k = 0; k < DCH; ++k)
      acc = fmaf(cv[b * DCH + k], cw[k * 512 + j], acc);
    if (j < 256) acc += 1.0f;
    gb[b * 512 + j] = acc;
  }
}

// ---------------- weight prep: transpose + split to bf16 hi/lo --------------
__global__ __launch_bounds__(256) void wprep0_kernel(const float* __restrict__ w0,
                                                     unsigned short* __restrict__ thi,
                                                     unsigned short* __restrict__ tlo) {
  int k = blockIdx.x;        // 0..831
  int n = threadIdx.x;       // 0..255
  float v = (k < INDIM) ? w0[(size_t)k * 256 + n] : 0.0f;
  unsigned short h, l;
  split_bf16(v, h, l);
  size_t o = (size_t)n * K0P + k;
  thi[o] = h; tlo[o] = l;
}
__global__ __launch_bounds__(256) void wpreph_kernel(const float* __restrict__ hw,
                                                     unsigned short* __restrict__ thi,
                                                     unsigned short* __restrict__ tlo) {
  int ik = blockIdx.x;       // i*256 + k
  int i = ik >> 8, k = ik & 255;
  int n = threadIdx.x;
  float v = hw[(size_t)ik * 256 + n];
  unsigned short h, l;
  split_bf16(v, h, l);
  size_t o = (size_t)i * 65536 + (size_t)n * 256 + k;
  thi[o] = h; tlo[o] = l;
}

// ---------------- antialiased triangle resize weights (jax.image.resize) ----
template <int SCALE>
__device__ __forceinline__ void mkw(int o, int nIn, float* w, int* ix) {
  const int TAPS = 2 * SCALE;
  float s = (float)(SCALE * o) + 0.5f * (float)(SCALE - 1);
  int j0 = SCALE * o + (SCALE - 2) / 2 - (SCALE - 1);
  float wsum = 0.f;
#pragma unroll
  for (int t = 0; t < TAPS; ++t) {
    int j = j0 + t;
    float wt = 1.0f - fabsf(s - (float)j) * (1.0f / (float)SCALE);
    bool valid = (j >= 0) && (j < nIn);
    wt = valid ? wt : 0.0f;
    ix[t] = valid ? j : 0;
    w[t] = wt;
    wsum += wt;
  }
  float inv = 1.0f / wsum;
#pragma unroll
  for (int t = 0; t < TAPS; ++t) w[t] *= inv;
}

// ---------------- separable resize: vertical then horizontal ----------------
template <int SCALE>
__global__ __launch_bounds__(256) void vpass_kernel(const float* __restrict__ g,
                                                    float* __restrict__ out) {
  const int HO = HGRID / SCALE;
  int pix = (blockIdx.x << 2) + (threadIdx.x >> 6);
  int lane = threadIdx.x & 63;
  int b = pix / (HO * HGRID);
  int rem = pix - b * (HO * HGRID);
  int oy = rem / HGRID, x = rem - (rem / HGRID) * HGRID;
  float wy[2 * SCALE]; int iy[2 * SCALE];
  mkw<SCALE>(oy, HGRID, wy, iy);
  float ax = 0.f, ay = 0.f, az = 0.f, aw = 0.f;
#pragma unroll
  for (int a = 0; a < 2 * SCALE; ++a) {
    if (wy[a] == 0.f) continue;
    const float4 v = *(const float4*)&g[((size_t)(b * HGRID + iy[a]) * HGRID + x) * DCH + lane * 4];
    ax = fmaf(wy[a], v.x, ax); ay = fmaf(wy[a], v.y, ay);
    az = fmaf(wy[a], v.z, az); aw = fmaf(wy[a], v.w, aw);
  }
  float4 r; r.x = ax; r.y = ay; r.z = az; r.w = aw;
  *(float4*)&out[(size_t)pix * DCH + lane * 4] = r;
}
template <int SCALE>
__global__ __launch_bounds__(256) void hpass_kernel(const float* __restrict__ v,
                                                    float* __restrict__ out) {
  const int HO = HGRID / SCALE, WO = HGRID / SCALE;
  int pix = (blockIdx.x << 2) + (threadIdx.x >> 6);
  int lane = threadIdx.x & 63;
  int b = pix / (HO * WO);
  int rem = pix - b * (HO * WO);
  int oy = rem / WO, ox = rem - (rem / WO) * WO;
  float wx[2 * SCALE]; int ix[2 * SCALE];
  mkw<SCALE>(ox, HGRID, wx, ix);
  float ax = 0.f, ay = 0.f, az = 0.f, aw = 0.f;
#pragma unroll
  for (int c = 0; c < 2 * SCALE; ++c) {
    if (wx[c] == 0.f) continue;
    const float4 t = *(const float4*)&v[((size_t)(b * HO + oy) * HGRID + ix[c]) * DCH + lane * 4];
    ax = fmaf(wx[c], t.x, ax); ay = fmaf(wx[c], t.y, ay);
    az = fmaf(wx[c], t.z, az); aw = fmaf(wx[c], t.w, aw);
  }
  float4 r; r.x = ax; r.y = ay; r.z = az; r.w = aw;
  *(float4*)&out[(size_t)pix * DCH + lane * 4] = r;
}

// ---------------- bilinear sample, split-bf16 write --------------------------
__device__ __forceinline__ void sample3(const float* __restrict__ g, int HW, int b,
                                        float cy, float cx, int lane,
                                        unsigned short* __restrict__ dhi,
                                        unsigned short* __restrict__ dlo) {
  float fm = (float)(HW - 1);
  float y = ((cy + 1.0f) * 0.5f) * fm;
  float x = ((cx + 1.0f) * 0.5f) * fm;
  float y0f = fminf(fmaxf(floorf(y), 0.0f), fm);
  float x0f = fminf(fmaxf(floorf(x), 0.0f), fm);
  int y0 = (int)y0f, x0 = (int)x0f;
  int y1 = min(y0 + 1, HW - 1), x1 = min(x0 + 1, HW - 1);
  float wy = y - y0f, wx = x - x0f;
  size_t bb = (size_t)b * HW * HW;
  const float4 v00 = *(const float4*)&g[(bb + (size_t)y0 * HW + x0) * DCH + lane * 4];
  const float4 v01 = *(const float4*)&g[(bb + (size_t)y0 * HW + x1) * DCH + lane * 4];
  const float4 v10 = *(const float4*)&g[(bb + (size_t)y1 * HW + x0) * DCH + lane * 4];
  const float4 v11 = *(const float4*)&g[(bb + (size_t)y1 * HW + x1) * DCH + lane * 4];
  float r[4];
  {
    float t0 = v00.x * (1.f - wx) + v01.x * wx, b0 = v10.x * (1.f - wx) + v11.x * wx;
    r[0] = t0 * (1.f - wy) + b0 * wy;
    float t1 = v00.y * (1.f - wx) + v01.y * wx, b1 = v10.y * (1.f - wx) + v11.y * wx;
    r[1] = t1 * (1.f - wy) + b1 * wy;
    float t2 = v00.z * (1.f - wx) + v01.z * wx, b2 = v10.z * (1.f - wx) + v11.z * wx;
    r[2] = t2 * (1.f - wy) + b2 * wy;
    float t3 = v00.w * (1.f - wx) + v01.w * wx, b3 = v10.w * (1.f - wx) + v11.w * wx;
    r[3] = t3 * (1.f - wy) + b3 * wy;
  }
  unsigned short h[4], l[4];
#pragma unroll
  for (int j = 0; j < 4; ++j) split_bf16(r[j], h[j], l[j]);
  ushort2 p;
  p.x = h[0]; p.y = h[1]; *(ushort2*)(dhi + lane * 4) = p;
  p.x = h[2]; p.y = h[3]; *(ushort2*)(dhi + lane * 4 + 2) = p;
  p.x = l[0]; p.y = l[1]; *(ushort2*)(dlo + lane * 4) = p;
  p.x = l[2]; p.y = l[3]; *(ushort2*)(dlo + lane * 4 + 2) = p;
}

// ---------------- assemble h0 row (split bf16 planes, pitch 832) ------------
__global__ __launch_bounds__(256) void assemble_kernel(
    const float* __restrict__ g0, const float* __restrict__ g1,
    const float* __restrict__ g2, const float* __restrict__ coords,
    const float* __restrict__ oracle, unsigned short* __restrict__ h0hi,
    unsigned short* __restrict__ h0lo, int row0, int nrows) {
  int lr = (blockIdx.x << 2) + (threadIdx.x >> 6);
  if (lr >= nrows) return;
  int lane = threadIdx.x & 63;
  int r = row0 + lr;
  int b = r >> 13, n = r & (NPTS - 1);
  float cy = coords[2 * n], cx = coords[2 * n + 1];
  unsigned short* rhi = h0hi + (size_t)lr * K0P;
  unsigned short* rlo = h0lo + (size_t)lr * K0P;
  if (lane < 45) {
    float val; int pos;
    if (lane < 2) { val = (lane == 0) ? cy : cx; pos = lane; }
    else if (lane < 42) {
      int q = lane - 2, f = q >> 2, m = q & 3;
      float ang = ((m & 1) ? cx : cy) * ldexpf(3.14159274101257324f, f);
      val = (m < 2) ? sinf(ang) : cosf(ang);
      pos = lane;
    } else { pos = 810 + (lane - 42); val = oracle[((size_t)b * NPTS + n) * 3 + (lane - 42)]; }
    unsigned short h, l; split_bf16(val, h, l);
    rhi[pos] = h; rlo[pos] = l;
  } else {
    int pos = INDIM + (lane - 45);  // 813..831
    rhi[pos] = 0; rlo[pos] = 0;
  }
  sample3(g0, 128, b, cy, cx, lane, rhi + 42, rlo + 42);
  sample3(g1, 64, b, cy, cx, lane, rhi + 42 + 256, rlo + 42 + 256);
  sample3(g2, 32, b, cy, cx, lane, rhi + 42 + 512, rlo + 42 + 512);
}

// ---------------- fused MLP: h0 -> L0 -> L1 -> L2 -> L3 -> out ---------------
// Block: 512 threads (8 waves), 64 rows, full 256-wide hidden state in LDS.
#define MFMA(a, b, c) __builtin_amdgcn_mfma_f32_32x32x16_bf16((a), (b), (c), 0, 0, 0)

__global__ __launch_bounds__(512, 2) void fused_mlp(
    const unsigned short* __restrict__ Ahi, const unsigned short* __restrict__ Alo,
    const unsigned short* __restrict__ W0h, const unsigned short* __restrict__ W0l,
    const unsigned short* __restrict__ WHh, const unsigned short* __restrict__ WHl,
    const float* __restrict__ b0, const float* __restrict__ bh,
    const float* __restrict__ gbg, const float* __restrict__ ow,
    const float* __restrict__ ob, float* __restrict__ outp, int row0) {
  // LDS: A-stage 16KB, B-stage 64KB, H (hidden state) 64KB, out_w 3KB
  __shared__ alignas(16) unsigned short SAh[4][8][16][8];
  __shared__ alignas(16) unsigned short SAl[4][8][16][8];
  __shared__ alignas(16) unsigned short SBh[16][8][16][8];
  __shared__ alignas(16) unsigned short SBl[16][8][16][8];
  __shared__ alignas(16) unsigned short Hh[4][32][16][8];
  __shared__ alignas(16) unsigned short Hl[4][32][16][8];
  __shared__ float owL[768];
  __shared__ float obL[4];

  const int tid = threadIdx.x;
  const int lane = tid & 63;
  const int wid = tid >> 6;          // 0..7
  const int wm = wid >> 2;           // 0..1 (row half)
  const int wn = wid & 3;            // 0..3 (col quarter)
  const int ri = lane & 15;
  const int kq = lane >> 4;          // 0..3 staging chunk
  const int rb = (lane >> 4) & 1;
  const int khalf = lane >> 5;
  const int wm2rb = wm * 2 + rb;
  const int bg0 = wn * 4 + rb;
  const int bg1 = wn * 4 + 2 + rb;
  const int mrow0 = blockIdx.x << 6; // pass-local row base
  const int b = (row0 + mrow0) >> 13;
  const int colb = wn * 64 + (lane & 31);

  // out_w / out_b to LDS (consumed at the end; later barriers cover it)
  owL[tid] = ow[tid];
  if (tid < 256) owL[512 + tid] = ow[512 + tid];
  if (tid < 3) obL[tid] = ob[tid];

  // gamma/beta hoisted to registers (col fixed per lane)
  float ga_r[2], be_r[2];
  {
    const float* gbb = gbg + ((size_t)b << 9);
    ga_r[0] = gbb[colb];       ga_r[1] = gbb[colb + 32];
    be_r[0] = gbb[256 + colb]; be_r[1] = gbb[256 + colb + 32];
  }

  f32x16 acc0, acc1;
#pragma unroll
  for (int i = 0; i < 16; ++i) { acc0[i] = 0.f; acc1[i] = 0.f; }

#define STAGE_A(kk)                                                              \
  {                                                                              \
    const unsigned short* ap_ = (wid < 4) ? Ahi : Alo;                           \
    unsigned short* db_ = (wid < 4) ? &SAh[wid & 3][0][0][0] : &SAl[wid & 3][0][0][0]; \
    const unsigned short* s_ =                                                   \
        ap_ + (size_t)(mrow0 + (wid & 3) * 16 + ri) * K0P + (kk) + kq * 8;       \
    gload16(s_, db_);                                                            \
    gload16(s_ + 32, db_ + 512);                                                 \
  }

#define STAGE_B(ph, pl, pitch, kk)                                               \
  {                                                                              \
    const unsigned short* s0_ = (ph) + (size_t)(wid * 16 + ri) * (pitch) + (kk) + kq * 8;       \
    const unsigned short* s1_ = (ph) + (size_t)((wid + 8) * 16 + ri) * (pitch) + (kk) + kq * 8; \
    gload16(s0_, &SBh[wid][0][0][0]);                                            \
    gload16(s0_ + 32, &SBh[wid][4][0][0]);                                       \
    gload16(s1_, &SBh[wid + 8][0][0][0]);                                        \
    gload16(s1_ + 32, &SBh[wid + 8][4][0][0]);                                   \
    const unsigned short* s2_ = (pl) + (size_t)(wid * 16 + ri) * (pitch) + (kk) + kq * 8;       \
    const unsigned short* s3_ = (pl) + (size_t)((wid + 8) * 16 + ri) * (pitch) + (kk) + kq * 8; \
    gload16(s2_, &SBl[wid][0][0][0]);                                            \
    gload16(s2_ + 32, &SBl[wid][4][0][0]);                                       \
    gload16(s3_, &SBl[wid + 8][0][0][0]);                                        \
    gload16(s3_ + 32, &SBl[wid + 8][4][0][0]);                                   \
  }

#define COMPUTE_STEP(AHX, ALX)                                                   \
  _Pragma("unroll") for (int t = 0; t < 4; ++t) {                                \
    short8 ah = *(const short8*)(AHX);                                           \
    short8 al = *(const short8*)(ALX);                                           \
    short8 bh0 = *(const short8*)&SBh[bg0][t * 2 + khalf][ri][0];                \
    short8 bl0 = *(const short8*)&SBl[bg0][t * 2 + khalf][ri][0];                \
    short8 bh1 = *(const short8*)&SBh[bg1][t * 2 + khalf][ri][0];                \
    short8 bl1 = *(const short8*)&SBl[bg1][t * 2 + khalf][ri][0];                \
    acc0 = MFMA(ah, bh0, acc0); acc1 = MFMA(ah, bh1, acc1);                      \
    acc0 = MFMA(ah, bl0, acc0); acc1 = MFMA(ah, bl1, acc1);                      \
    acc0 = MFMA(al, bh0, acc0); acc1 = MFMA(al, bh1, acc1);                      \
  }

#define EPILOGUE(bptr)                                                           \
  {                                                                              \
    _Pragma("unroll") for (int ni = 0; ni < 2; ++ni) {                           \
      int col_ = colb + ni * 32;                                                 \
      float bi_ = (bptr)[col_];                                                  \
      float ga_ = ga_r[ni], be_ = be_r[ni];                                      \
      const f32x16 av_ = ni ? acc1 : acc0;                                       \
      int kcw_ = col_ >> 3, jw_ = col_ & 7;                                      \
      _Pragma("unroll") for (int reg = 0; reg < 16; ++reg) {                     \
        int riw_ = (reg & 3) + 8 * ((reg >> 2) & 1) + 4 * khalf;                 \
        int rgw_ = wm * 2 + (reg >> 3);                                          \
        float v_ = gelu_f((av_[reg] + bi_) * ga_ + be_);                         \
        unsigned short hh_, ll_;                                                 \
        split_bf16(v_, hh_, ll_);                                                \
        Hh[rgw_][kcw_][riw_][jw_] = hh_;                                         \
        Hl[rgw_][kcw_][riw_][jw_] = ll_;                                         \
      }                                                                          \
    }                                                                            \
  }

  // ---- Layer 0: K = 832, A streamed from HBM ----
#pragma unroll 1
  for (int s = 0; s < 13; ++s) {
    const int k0 = s * 64;
    STAGE_A(k0);
    STAGE_B(W0h, W0l, K0P, k0);
    __syncthreads();
    COMPUTE_STEP(&SAh[wm2rb][t * 2 + khalf][ri][0], &SAl[wm2rb][t * 2 + khalf][ri][0]);
    __syncthreads();
  }
  EPILOGUE(b0);
  __syncthreads();

  // ---- Hidden layers: K = 256, A from H (LDS) ----
#pragma unroll 1
  for (int li = 0; li < 3; ++li) {
    const unsigned short* whb = WHh + (size_t)li * 65536;
    const unsigned short* wlb = WHl + (size_t)li * 65536;
#pragma unroll
    for (int i = 0; i < 16; ++i) { acc0[i] = 0.f; acc1[i] = 0.f; }
#pragma unroll 1
    for (int s = 0; s < 4; ++s) {
      const int k0 = s * 64;
      STAGE_B(whb, wlb, 256, k0);
      __syncthreads();
      COMPUTE_STEP(&Hh[wm2rb][s * 8 + t * 2 + khalf][ri][0],
                   &Hl[wm2rb][s * 8 + t * 2 + khalf][ri][0]);
      __syncthreads();
    }
    EPILOGUE(bh + li * 256);
    __syncthreads();
  }

  // ---- out projection: 256 -> 3 + tanh ----
  {
    int row = tid >> 3;
    int kc0 = (tid & 7) * 4;
    int rgo = row >> 4, rio = row & 15;
    float s0 = 0.f, s1 = 0.f, s2 = 0.f;
#pragma unroll
    for (int c = 0; c < 4; ++c) {
      short8 hh = *(const short8*)&Hh[rgo][kc0 + c][rio][0];
      short8 hl = *(const short8*)&Hl[rgo][kc0 + c][rio][0];
#pragma unroll
      for (int j = 0; j < 8; ++j) {
        float hv = b2f((unsigned short)hh[j]) + b2f((unsigned short)hl[j]);
        int k = (kc0 + c) * 8 + j;
        s0 = fmaf(hv, owL[k * 3 + 0], s0);
        s1 = fmaf(hv, owL[k * 3 + 1], s1);
        s2 = fmaf(hv, owL[k * 3 + 2], s2);
      }
    }
#pragma unroll
    for (int off = 1; off < 8; off <<= 1) {
      s0 += __shfl_xor(s0, off);
      s1 += __shfl_xor(s1, off);
      s2 += __shfl_xor(s2, off);
    }
    if ((tid & 7) == 0) {
      size_t r = (size_t)(row0 + mrow0 + row);
      outp[r * 3 + 0] = tanhf(s0 + obL[0]);
      outp[r * 3 + 1] = tanhf(s1 + obL[1]);
      outp[r * 3 + 2] = tanhf(s2 + obL[2]);
    }
  }
#undef STAGE_A
#undef STAGE_B
#undef COMPUTE_STEP
#undef EPILOGUE
}

extern "C" void kernel_launch(void* const* d_in, const int* in_sizes, int n_in,
                              void* d_out, int out_size, void* d_ws, size_t ws_size,
                              hipStream_t stream) {
  const float* feature_grid = (const float*)d_in[0];
  const float* context_vec = (const float*)d_in[1];
  const float* coords = (const float*)d_in[2];
  const float* oracle = (const float*)d_in[3];
  const float* mlp0_w = (const float*)d_in[4];
  const float* mlp0_b = (const float*)d_in[5];
  const float* mlp_hw = (const float*)d_in[6];
  const float* mlp_hb = (const float*)d_in[7];
  const float* ctx_w = (const float*)d_in[8];
  const float* ctx_b = (const float*)d_in[9];
  const float* out_w = (const float*)d_in[10];
  const float* out_b = (const float*)d_in[11];
  float* out = (float*)d_out;

  // ---- workspace layout (bytes) ----
  char* p = (char*)d_ws;
  float* gb = (float*)p;                 p += 8 * 512 * 4;
  unsigned short* w0t_hi = (unsigned short*)p; p += (size_t)256 * K0P * 2;
  unsigned short* w0t_lo = (unsigned short*)p; p += (size_t)256 * K0P * 2;
  unsigned short* wht_hi = (unsigned short*)p; p += (size_t)3 * 65536 * 2;
  unsigned short* wht_lo = (unsigned short*)p; p += (size_t)3 * 65536 * 2;
  float* lvl1 = (float*)p;               p += (size_t)8 * 64 * 64 * 256 * 4;
  float* lvl2 = (float*)p;               p += (size_t)8 * 32 * 32 * 256 * 4;
  float* vtmp = (float*)p;               p += (size_t)8 * 64 * 128 * 256 * 4;
  size_t fixed_bytes = (size_t)(p - (char*)d_ws);
  size_t per_row_bytes = (size_t)K0P * 2 * 2;  // h0 hi+lo only
  long long cap = 0;
  if (ws_size > fixed_bytes) cap = (long long)((ws_size - fixed_bytes) / per_row_bytes);
  if (cap > TOTROWS) cap = TOTROWS;
  cap &= ~127LL;
  if (cap < 128) cap = 128;
  unsigned short* h0hi = (unsigned short*)p;
  unsigned short* h0lo = h0hi + (size_t)cap * K0P;

  hipLaunchKernelGGL(ctx_kernel, dim3(8), dim3(256), 0, stream, context_vec, ctx_w, ctx_b, gb);
  hipLaunchKernelGGL(wprep0_kernel, dim3(K0P), dim3(256), 0, stream, mlp0_w, w0t_hi, w0t_lo);
  hipLaunchKernelGGL(wpreph_kernel, dim3(3 * 256), dim3(256), 0, stream, mlp_hw, wht_hi, wht_lo);
  hipLaunchKernelGGL((vpass_kernel<2>), dim3(8 * 64 * 128 / 4), dim3(256), 0, stream,
                     feature_grid, vtmp);
  hipLaunchKernelGGL((hpass_kernel<2>), dim3(8 * 64 * 64 / 4), dim3(256), 0, stream, vtmp, lvl1);
  hipLaunchKernelGGL((vpass_kernel<4>), dim3(8 * 32 * 128 / 4), dim3(256), 0, stream,
                     feature_grid, vtmp);
  hipLaunchKernelGGL((hpass_kernel<4>), dim3(8 * 32 * 32 / 4), dim3(256), 0, stream, vtmp, lvl2);

  int npass = (int)((TOTROWS + cap - 1) / cap);
  for (int ps = 0; ps < npass; ++ps) {
    int row0 = (int)((long long)ps * cap);
    int nrows = TOTROWS - row0;
    if (nrows > cap) nrows = (int)cap;
    int pb = (nrows + 3) >> 2;
    hipLaunchKernelGGL(assemble_kernel, dim3(pb), dim3(256), 0, stream, feature_grid,
                       lvl1, lvl2, coords, oracle, h0hi, h0lo, row0, nrows);
    hipLaunchKernelGGL(fused_mlp, dim3(nrows >> 6), dim3(512), 0, stream,
                       h0hi, h0lo, w0t_hi, w0t_lo, wht_hi, wht_lo,
                       mlp0_b, mlp_hb, gb, out_w, out_b, out, row0);
  }
}